// Round 7
// baseline (69.250 us; speedup 1.0000x reference)
//
#include <hip/hip_runtime.h>
#include <math.h>

#define B_   16
#define T_   2048
#define DIM_ 512
#define M_   (B_*T_)
#define AP   520   // As row stride in shorts (1040 B): bank pattern 4i -> 2-way (free)

typedef __attribute__((ext_vector_type(8))) short short8_t;   // 8 x bf16 bits
typedef __attribute__((ext_vector_type(4))) float f32x4;

__device__ __forceinline__ float clamp01(float x){ return fminf(fmaxf(x,0.f),1.f); }
__device__ __forceinline__ float clampf(float x,float lo,float hi){ return fminf(fmaxf(x,lo),hi); }
__device__ __forceinline__ float gelu_exact(float x){ return 0.5f*x*(1.f+erff(x*0.70710678118654752f)); }
__device__ __forceinline__ unsigned short bf16_rne(float f){
  unsigned u = __float_as_uint(f);
  unsigned r = (u + 0x7fffu + ((u>>16)&1u)) >> 16;
  return (unsigned short)r;
}
__device__ __forceinline__ float fast_tanh(float x){
  float e = __expf(2.0f*x);
  return 1.0f - 2.0f*__builtin_amdgcn_rcpf(e + 1.0f);
}
// tanh-form GELU (max abs dev from exact ~3e-4; used only in the wide epilogue)
__device__ __forceinline__ float gelu_fast(float x){
  float u = 0.7978845608028654f*fmaf(0.044715f*x, x*x, x);
  return 0.5f*x*(1.f + fast_tanh(u));
}
// packed f32x2 -> bf16x2 (RNE), 1 instruction
__device__ __forceinline__ unsigned cvt_pk_bf16(float lo, float hi){
  unsigned r;
  asm("v_cvt_pk_bf16_f32 %0, %1, %2" : "=v"(r) : "v"(lo), "v"(hi));
  return r;
}
__device__ __forceinline__ int idx32(int t){ return t + (t>>5); }  // pad stride 33

// ---------------------------------------------------------------------------
// P1: 160 blocks x 512 threads.
//  blk   0..127 : spk_ctx[b, s*64 .. s*64+64)  (b=blk>>3, s=blk&7)
//  blk 128..143 : EMA scan + excl cumsum       (b=blk-128)
//  blk 144..159 : rW1[0:512] -> bf16 Bt[kt][col][kk]  (kt=blk-144)
// ---------------------------------------------------------------------------
__global__ __launch_bounds__(512) void k_p1(
    const float* __restrict__ log_anchor, const float* __restrict__ unit_mask,
    const float* __restrict__ sealed_mask, const float* __restrict__ silence_mask,
    const float* __restrict__ local_rate_ema,
    const float* __restrict__ spk_embed, const float* __restrict__ spk_W,
    const float* __restrict__ spk_b, const float* __restrict__ rW1,
    float* __restrict__ lr_seq, float* __restrict__ prefix_prev,
    float* __restrict__ spk_ctx, unsigned short* __restrict__ BtG)
{
  __shared__ float shbuf[12672];
  const int tid = threadIdx.x;
  const int blk = blockIdx.x;

  if (blk < 128){
    const int b = blk >> 3, n0 = (blk & 7)*64;
    float* se      = shbuf;
    float* partial = shbuf + 512;
    se[tid] = spk_embed[b*512 + tid];
    __syncthreads();
    const int nq = tid & 15, q = tid >> 4;
    float a0=0.f, a1=0.f, a2=0.f, a3=0.f;
    const float* wp = spk_W + (q*16)*512 + n0 + nq*4;
    #pragma unroll
    for (int kk = 0; kk < 16; ++kk){
      float s = se[q*16 + kk];
      float4 v = *(const float4*)(wp + kk*512);
      a0 = fmaf(s, v.x, a0); a1 = fmaf(s, v.y, a1);
      a2 = fmaf(s, v.z, a2); a3 = fmaf(s, v.w, a3);
    }
    *(float4*)&partial[q*64 + nq*4] = make_float4(a0,a1,a2,a3);
    __syncthreads();
    if (tid < 64){
      float acc = spk_b[n0 + tid];
      #pragma unroll
      for (int qq = 0; qq < 32; ++qq) acc += partial[qq*64 + tid];
      spk_ctx[b*512 + n0 + tid] = tanhf(acc);
    }

  } else if (blk < 144){
    const int b = blk - 128;
    float* s_la = shbuf;
    float* s_um = shbuf + 2112;
    float* s_sm = shbuf + 4224;
    float* s_si = shbuf + 6336;
    float* s_or = shbuf + 8448;
    float* s_op = shbuf + 10560;
    #pragma unroll
    for (int p = 0; p < 4; ++p){
      int t = tid + p*512, g = b*T_ + t, ix = idx32(t);
      s_la[ix] = log_anchor[g];
      s_um[ix] = unit_mask[g];
      s_sm[ix] = sealed_mask[g];
      s_si[ix] = silence_mask[g];
    }
    __syncthreads();
    if (tid < 64){
      const float CE = (float)(1.0 - 0.95);
      const int base = tid*32;
      float A = 1.f, Bv = 0.f, S = 0.f;
      for (int j = 0; j < 32; ++j){
        int ix = idx32(base + j);
        float mask   = clamp01(s_um[ix]);
        float sealed = clamp01(s_sm[ix]);
        float sil    = clamp01(s_si[ix])*mask;
        float speech = mask*sealed*(1.f-sil);
        float cm = CE*speech;
        A  = (1.f-cm)*A;
        Bv = (1.f-cm)*Bv + cm*s_la[ix];
        S += speech;
      }
      float Ai=A, Bi=Bv, Si=S;
      for (int off = 1; off < 64; off <<= 1){
        float Ap=__shfl_up(Ai,off), Bp=__shfl_up(Bi,off), Sp=__shfl_up(Si,off);
        if (tid >= off){ Bi = Ai*Bp + Bi; Ai *= Ap; Si += Sp; }
      }
      float Ae=__shfl_up(Ai,1), Be=__shfl_up(Bi,1), Se=__shfl_up(Si,1);
      if (tid==0){ Ae=1.f; Be=0.f; Se=0.f; }
      float r  = Ae*local_rate_ema[b] + Be;
      float ps = Se;
      for (int j = 0; j < 32; ++j){
        int ix = idx32(base + j);
        float mask   = clamp01(s_um[ix]);
        float sealed = clamp01(s_sm[ix]);
        float sil    = clamp01(s_si[ix])*mask;
        float speech = mask*sealed*(1.f-sil);
        s_or[ix] = r;
        s_op[ix] = ps;
        r  += CE*speech*(s_la[ix]-r);
        ps += speech;
      }
    }
    __syncthreads();
    #pragma unroll
    for (int p = 0; p < 4; ++p){
      int t = tid + p*512, g = b*T_ + t, ix = idx32(t);
      lr_seq[g]      = s_or[ix];
      prefix_prev[g] = s_op[ix];
    }

  } else {
    const int kt = blk - 144;
    unsigned short* sb = (unsigned short*)shbuf;   // [32][512]
    #pragma unroll
    for (int p = 0; p < 32; ++p){
      int id = tid + p*512;
      int kl = id >> 9, col = id & 511;
      sb[kl*512 + col] = bf16_rne(rW1[(kt*32 + kl)*512 + col]);
    }
    __syncthreads();
    const int col = tid;
    unsigned q[16];
    #pragma unroll
    for (int p = 0; p < 16; ++p)
      q[p] = (unsigned)sb[(2*p)*512 + col] | ((unsigned)sb[(2*p+1)*512 + col] << 16);
    uint4* dst = (uint4*)(BtG + kt*16384 + col*32);
    dst[0] = make_uint4(q[0], q[1], q[2], q[3]);
    dst[1] = make_uint4(q[4], q[5], q[6], q[7]);
    dst[2] = make_uint4(q[8], q[9], q[10], q[11]);
    dst[3] = make_uint4(q[12], q[13], q[14], q[15]);
  }
}

// ---------------------------------------------------------------------------
// P2: 256 blocks x 512 threads.
//  blk   0..127 : spk_pb[b, slice] = sc@rW1[512:1024,slice] + rb1
//  blk 128..255 : cpart[b][s] = sum_slice gelu(ac)*cW2   (coarse partials)
// ---------------------------------------------------------------------------
__global__ __launch_bounds__(512) void k_p2(
    const float* __restrict__ spk_ctx, const float* __restrict__ global_rate,
    const float* __restrict__ cW1, const float* __restrict__ cb1,
    const float* __restrict__ cW2, const float* __restrict__ rW1,
    const float* __restrict__ rb1,
    float* __restrict__ spk_pb, float* __restrict__ cpart)
{
  __shared__ float sc[512];
  __shared__ float partial[32*64];
  const int tid = threadIdx.x;
  const int blk = blockIdx.x;
  const bool isAC = blk >= 128;
  const int bb = isAC ? (blk - 128) : blk;
  const int b = bb >> 3, s = bb & 7, n0 = s*64;

  sc[tid] = spk_ctx[b*512 + tid];
  __syncthreads();
  const int nq = tid & 15, q = tid >> 4;
  const float* mat = isAC ? cW1 : (rW1 + 512*512);
  float a0=0.f, a1=0.f, a2=0.f, a3=0.f;
  const float* wp = mat + (q*16)*512 + n0 + nq*4;
  #pragma unroll
  for (int kk = 0; kk < 16; ++kk){
    float sv = sc[q*16 + kk];
    float4 v = *(const float4*)(wp + kk*512);
    a0 = fmaf(sv, v.x, a0); a1 = fmaf(sv, v.y, a1);
    a2 = fmaf(sv, v.z, a2); a3 = fmaf(sv, v.w, a3);
  }
  *(float4*)&partial[q*64 + nq*4] = make_float4(a0,a1,a2,a3);
  __syncthreads();
  if (tid < 64){
    const int n = n0 + tid;
    float acc = 0.f;
    #pragma unroll
    for (int qq = 0; qq < 32; ++qq) acc += partial[qq*64 + tid];
    if (!isAC){
      spk_pb[b*512 + n] = acc + rb1[n];
    } else {
      float ac = acc + cb1[n] + global_rate[b]*cW1[512*512 + n];
      float g  = gelu_exact(ac)*cW2[n];
      g += __shfl_xor(g,1);  g += __shfl_xor(g,2);  g += __shfl_xor(g,4);
      g += __shfl_xor(g,8);  g += __shfl_xor(g,16); g += __shfl_xor(g,32);
      if (tid == 0) cpart[b*8 + s] = g;
    }
  }
}

// ---------------------------------------------------------------------------
// K3: MFMA heavy kernel. Block = 16 waves (1024 thr), 64 rows x 512 cols.
// Wave w: rh = w>>3 (row half, 32 rows), cc = w&7 (64-col chunk).
// acc[2][4] = 32 AGPR; target ~65-95 VGPR -> fits __launch_bounds__(1024,4)
// (128-reg cap) without spilling => 4 waves/SIMD resident.
// Full-K A tile (64x512 bf16, AP=520 -> 66.5 KB LDS), A computed once,
// kt-loop barrier-free (ds_read A + L2 B-fragments + 8 MFMA per step).
// ---------------------------------------------------------------------------
__global__ __launch_bounds__(1024, 4) void k_heavy(
    const int*   __restrict__ content_units, const float* __restrict__ log_anchor,
    const float* __restrict__ unit_mask,     const float* __restrict__ sealed_mask,
    const float* __restrict__ sep_hint,      const float* __restrict__ edge_cue,
    const float* __restrict__ global_rate,   const float* __restrict__ silence_mask,
    const float* __restrict__ embed,         const float* __restrict__ feat_W,
    const float* __restrict__ feat_b,        const float* __restrict__ rW1,
    const float* __restrict__ rW2,           const float* __restrict__ rb2,
    const float* __restrict__ cb2,
    const float* __restrict__ lr_seq,        const float* __restrict__ prefix_prev,
    const float* __restrict__ spk_pb,        const float* __restrict__ cpart,
    const unsigned short* __restrict__ BtG,
    float* __restrict__ out)
{
  __shared__ unsigned short As_s[64*AP];    // 66560 B
  __shared__ float r_la[64], r_lr[64], r_sil[64], r_sep[64], r_edge[64], r_mask[64];
  __shared__ int   r_u[64];
  __shared__ float r_gt[64], r_speech[64], r_silc[64], r_resmul[64], r_tau[64];
  __shared__ float pdred[16][32];

  const int m0   = blockIdx.x*64;
  const int b    = m0 >> 11;
  const int tid  = threadIdx.x;
  const int lane = tid & 63;
  const int w    = tid >> 6;                // 0..15
  const int rh   = w >> 3, cc = w & 7;
  const int l15  = lane & 15, kg = lane >> 4;

  if (tid < 64){
    int m = m0 + tid;
    float csum = cb2[0];
    #pragma unroll
    for (int s = 0; s < 8; ++s) csum += cpart[b*8 + s];
    float coarse = 0.2f*tanhf(csum);
    float mask   = clamp01(unit_mask[m]);
    float sealed = clamp01(sealed_mask[m]);
    float sil    = clamp01(silence_mask[m])*mask;
    float commit = mask*sealed;
    float silc   = commit*sil;
    float speech = commit*(1.f-sil);
    float la = log_anchor[m];
    float lr = lr_seq[m];
    float gap = clampf(global_rate[b]-lr, -0.35f, 0.35f)*commit;
    float gt  = (gap + coarse*commit)*commit;
    float cold = clamp01(prefix_prev[m]*0.5f);
    float dur  = expf(la);
    float shortv = clamp01(fmaxf(dur,1.f)-1.f);
    r_la[tid]=la; r_lr[tid]=lr; r_sil[tid]=sil;
    r_sep[tid]=sep_hint[m]; r_edge[tid]=edge_cue[m]; r_mask[tid]=mask;
    r_u[tid]=content_units[m];
    r_gt[tid]=gt; r_speech[tid]=speech; r_silc[tid]=silc;
    r_resmul[tid]=cold*shortv*speech;
    r_tau[tid]=0.35f*((dur<2.0f)?0.35f:1.0f);
  }
  __syncthreads();

  // ---- A-compute: thread = 2 rows x 16 k, processed in 4-element pieces ----
  {
    const int rp   = (tid >> 5) << 1;       // row pair base
    const int kseg = (tid & 31) * 16;       // k segment start
    const int   u0 = r_u[rp],   u1 = r_u[rp+1];
    const float la0=r_la[rp],  lr0=r_lr[rp],  si0=r_sil[rp],
                sp0=r_sep[rp], ed0=r_edge[rp], mk0=r_mask[rp];
    const float la1=r_la[rp+1], lr1=r_lr[rp+1], si1=r_sil[rp+1],
                sp1=r_sep[rp+1], ed1=r_edge[rp+1], mk1=r_mask[rp+1];
    #pragma unroll
    for (int c4 = 0; c4 < 4; ++c4){
      const int jg = kseg + c4*4;
      const float4 w0 = *(const float4*)(feat_W + jg);
      const float4 w1 = *(const float4*)(feat_W + 512 + jg);
      const float4 w2 = *(const float4*)(feat_W + 1024 + jg);
      const float4 w3 = *(const float4*)(feat_W + 1536 + jg);
      const float4 w4 = *(const float4*)(feat_W + 2048 + jg);
      const float4 bb = *(const float4*)(feat_b + jg);
      {
        const float4 e = *(const float4*)(embed + (size_t)u0*DIM_ + jg);
        float f0 = e.x + bb.x + la0*w0.x + lr0*w1.x + si0*w2.x + sp0*w3.x + ed0*w4.x;
        float f1 = e.y + bb.y + la0*w0.y + lr0*w1.y + si0*w2.y + sp0*w3.y + ed0*w4.y;
        float f2 = e.z + bb.z + la0*w0.z + lr0*w1.z + si0*w2.z + sp0*w3.z + ed0*w4.z;
        float f3 = e.w + bb.w + la0*w0.w + lr0*w1.w + si0*w2.w + sp0*w3.w + ed0*w4.w;
        unsigned p0 = cvt_pk_bf16(fast_tanh(f0)*mk0, fast_tanh(f1)*mk0);
        unsigned p1 = cvt_pk_bf16(fast_tanh(f2)*mk0, fast_tanh(f3)*mk0);
        *(uint2*)&As_s[rp*AP + jg] = make_uint2(p0, p1);
      }
      {
        const float4 e = *(const float4*)(embed + (size_t)u1*DIM_ + jg);
        float f0 = e.x + bb.x + la1*w0.x + lr1*w1.x + si1*w2.x + sp1*w3.x + ed1*w4.x;
        float f1 = e.y + bb.y + la1*w0.y + lr1*w1.y + si1*w2.y + sp1*w3.y + ed1*w4.y;
        float f2 = e.z + bb.z + la1*w0.z + lr1*w1.z + si1*w2.z + sp1*w3.z + ed1*w4.z;
        float f3 = e.w + bb.w + la1*w0.w + lr1*w1.w + si1*w2.w + sp1*w3.w + ed1*w4.w;
        unsigned p0 = cvt_pk_bf16(fast_tanh(f0)*mk1, fast_tanh(f1)*mk1);
        unsigned p1 = cvt_pk_bf16(fast_tanh(f2)*mk1, fast_tanh(f3)*mk1);
        *(uint2*)&As_s[(rp+1)*AP + jg] = make_uint2(p0, p1);
      }
    }
  }
  __syncthreads();   // As ready; no more barriers until epilogue

  f32x4 acc[2][4];
  #pragma unroll
  for (int r=0;r<2;++r)
    #pragma unroll
    for (int c=0;c<4;++c) acc[r][c] = (f32x4)0.0f;

  const unsigned short* bwave = BtG + (cc*64 + l15)*32 + kg*8;
  const int arow = rh*32;

  #pragma unroll 2
  for (int kt = 0; kt < 16; ++kt){
    const unsigned short* bkt = bwave + kt*16384;
    short8_t af[2], bfr[4];
    #pragma unroll
    for (int r=0;r<2;++r)
      af[r] = *(const short8_t*)&As_s[(arow + r*16 + l15)*AP + kt*32 + kg*8];
    #pragma unroll
    for (int c=0;c<4;++c)
      bfr[c] = *(const short8_t*)(bkt + c*512);
    #pragma unroll
    for (int r=0;r<2;++r)
      #pragma unroll
      for (int c=0;c<4;++c)
        acc[r][c] = __builtin_amdgcn_mfma_f32_16x16x32_bf16(af[r], bfr[c], acc[r][c], 0, 0, 0);
  }

  // --- epilogue: x = acc + spk_pb[col] + gt[row]*wb[col]; gelu; dot rW2 ---
  const int colb = cc*64 + l15;
  float stv[4], wbv[4], w2v[4];
  #pragma unroll
  for (int c=0;c<4;++c){
    int col = colb + c*16;
    stv[c] = spk_pb[b*DIM_ + col];
    wbv[c] = rW1[1024*DIM_ + col];
    w2v[c] = rW2[col];
  }
  #pragma unroll
  for (int r=0;r<2;++r){
    #pragma unroll
    for (int g=0; g<4; ++g){
      int lrow = r*16 + kg*4 + g;          // local row 0..31; C/D: row=(lane>>4)*4+reg
      float gt = r_gt[arow + lrow];
      float s = 0.f;
      #pragma unroll
      for (int c=0;c<4;++c){
        float x = acc[r][c][g] + stv[c] + gt*wbv[c];
        s += gelu_fast(x)*w2v[c];
      }
      s += __shfl_xor(s,1); s += __shfl_xor(s,2);
      s += __shfl_xor(s,4); s += __shfl_xor(s,8);
      if (l15 == 0) pdred[w][lrow] = s;
    }
  }
  __syncthreads();
  if (tid < 64){
    const int lrh = tid >> 5, lrow = tid & 31;
    float v = rb2[0];
    #pragma unroll
    for (int q = 0; q < 8; ++q) v += pdred[lrh*8 + q][lrow];
    float residual = 0.35f*tanhf(v) * r_resmul[tid];
    float gt = r_gt[tid];
    out[m0+tid] = clampf(gt + residual, -1.2f, 1.2f)*r_speech[tid]
                + clampf(gt, -r_tau[tid], r_tau[tid])*r_silc[tid];
  }
}

// ---------------------------------------------------------------------------
extern "C" void kernel_launch(void* const* d_in, const int* in_sizes, int n_in,
                              void* d_out, int out_size, void* d_ws, size_t ws_size,
                              hipStream_t stream)
{
  const int*   content_units  = (const int*)  d_in[0];
  const float* log_anchor     = (const float*)d_in[1];
  const float* unit_mask      = (const float*)d_in[2];
  const float* sealed_mask    = (const float*)d_in[3];
  const float* sep_hint       = (const float*)d_in[4];
  const float* edge_cue       = (const float*)d_in[5];
  const float* global_rate    = (const float*)d_in[6];
  const float* local_rate_ema = (const float*)d_in[7];
  const float* silence_mask   = (const float*)d_in[8];
  const float* spk_embed      = (const float*)d_in[9];
  const float* embed          = (const float*)d_in[10];
  const float* feat_W         = (const float*)d_in[11];
  const float* feat_b         = (const float*)d_in[12];
  const float* spk_W          = (const float*)d_in[13];
  const float* spk_b          = (const float*)d_in[14];
  const float* cW1            = (const float*)d_in[15];
  const float* cb1            = (const float*)d_in[16];
  const float* cW2            = (const float*)d_in[17];
  const float* cb2            = (const float*)d_in[18];
  const float* rW1            = (const float*)d_in[19];
  const float* rb1            = (const float*)d_in[20];
  const float* rW2            = (const float*)d_in[21];
  const float* rb2            = (const float*)d_in[22];
  float* out = (float*)d_out;

  float* ws       = (float*)d_ws;
  float* lr_seq   = ws;                  // 32768
  float* prefix   = ws + 32768;          // 32768
  float* spk_ctx  = ws + 65536;          // 8192
  float* spk_pb   = ws + 73728;          // 8192
  float* cpart    = ws + 81920;          // 128
  unsigned short* BtG = (unsigned short*)(ws + 82048);   // 512 KB bf16

  k_p1<<<160, 512, 0, stream>>>(log_anchor, unit_mask, sealed_mask, silence_mask,
                                local_rate_ema, spk_embed, spk_W, spk_b, rW1,
                                lr_seq, prefix, spk_ctx, BtG);
  k_p2<<<256, 512, 0, stream>>>(spk_ctx, global_rate, cW1, cb1, cW2, rW1, rb1,
                                spk_pb, cpart);
  k_heavy<<<M_/64, 1024, 0, stream>>>(content_units, log_anchor, unit_mask, sealed_mask,
                                      sep_hint, edge_cue, global_rate, silence_mask,
                                      embed, feat_W, feat_b, rW1, rW2, rb2, cb2,
                                      lr_seq, prefix, spk_pb, cpart, BtG, out);
}

// Round 8
// 55.274 us; speedup vs baseline: 1.2529x; 1.2529x over previous
//
#include <hip/hip_runtime.h>
#include <math.h>

#define B_    16
#define T_    2048
#define DIM_  512
#define M_    (B_*T_)
#define ASP   264     // A LDS row stride in shorts (528B): 16B-aligned, 2-way bank (free)
#define BCS   40      // B col stride in shorts (80B): 16B-aligned, 2-way bank (free)
#define BSLAB 20480   // shorts per kt slab: 512 cols * 40

typedef __attribute__((ext_vector_type(8))) short short8_t;   // 8 x bf16 bits
typedef __attribute__((ext_vector_type(4))) float f32x4;

__device__ __forceinline__ float clamp01(float x){ return fminf(fmaxf(x,0.f),1.f); }
__device__ __forceinline__ float clampf(float x,float lo,float hi){ return fminf(fmaxf(x,lo),hi); }
__device__ __forceinline__ float gelu_exact(float x){ return 0.5f*x*(1.f+erff(x*0.70710678118654752f)); }
__device__ __forceinline__ unsigned short bf16_rne(float f){
  unsigned u = __float_as_uint(f);
  unsigned r = (u + 0x7fffu + ((u>>16)&1u)) >> 16;
  return (unsigned short)r;
}
__device__ __forceinline__ float fast_tanh(float x){
  float e = __expf(2.0f*x);
  return 1.0f - 2.0f*__builtin_amdgcn_rcpf(e + 1.0f);
}
// tanh-form GELU (max abs dev ~3e-4; used only in the wide epilogue)
__device__ __forceinline__ float gelu_fast(float x){
  float u = 0.7978845608028654f*fmaf(0.044715f*x, x*x, x);
  return 0.5f*x*(1.f + fast_tanh(u));
}
__device__ __forceinline__ unsigned cvt_pk_bf16(float lo, float hi){
  unsigned r;
  asm("v_cvt_pk_bf16_f32 %0, %1, %2" : "=v"(r) : "v"(lo), "v"(hi));
  return r;
}
__device__ __forceinline__ int idx32(int t){ return t + (t>>5); }  // pad stride 33

// ---------------------------------------------------------------------------
// P1: 160 blocks x 512 threads.
//  blk   0..127 : spk_ctx[b, s*64 .. s*64+64)  (b=blk>>3, s=blk&7)
//  blk 128..143 : EMA scan + excl cumsum       (b=blk-128)
//  blk 144..159 : rW1[0:512] -> bf16 Bt[kt][col][40-pad]  (kt=blk-144)
// ---------------------------------------------------------------------------
__global__ __launch_bounds__(512) void k_p1(
    const float* __restrict__ log_anchor, const float* __restrict__ unit_mask,
    const float* __restrict__ sealed_mask, const float* __restrict__ silence_mask,
    const float* __restrict__ local_rate_ema,
    const float* __restrict__ spk_embed, const float* __restrict__ spk_W,
    const float* __restrict__ spk_b, const float* __restrict__ rW1,
    float* __restrict__ lr_seq, float* __restrict__ prefix_prev,
    float* __restrict__ spk_ctx, unsigned short* __restrict__ BtG)
{
  __shared__ float shbuf[12672];
  const int tid = threadIdx.x;
  const int blk = blockIdx.x;

  if (blk < 128){
    const int b = blk >> 3, n0 = (blk & 7)*64;
    float* se      = shbuf;
    float* partial = shbuf + 512;
    se[tid] = spk_embed[b*512 + tid];
    __syncthreads();
    const int nq = tid & 15, q = tid >> 4;
    float a0=0.f, a1=0.f, a2=0.f, a3=0.f;
    const float* wp = spk_W + (q*16)*512 + n0 + nq*4;
    #pragma unroll
    for (int kk = 0; kk < 16; ++kk){
      float s = se[q*16 + kk];
      float4 v = *(const float4*)(wp + kk*512);
      a0 = fmaf(s, v.x, a0); a1 = fmaf(s, v.y, a1);
      a2 = fmaf(s, v.z, a2); a3 = fmaf(s, v.w, a3);
    }
    *(float4*)&partial[q*64 + nq*4] = make_float4(a0,a1,a2,a3);
    __syncthreads();
    if (tid < 64){
      float acc = spk_b[n0 + tid];
      #pragma unroll
      for (int qq = 0; qq < 32; ++qq) acc += partial[qq*64 + tid];
      spk_ctx[b*512 + n0 + tid] = tanhf(acc);
    }

  } else if (blk < 144){
    const int b = blk - 128;
    float* s_la = shbuf;
    float* s_um = shbuf + 2112;
    float* s_sm = shbuf + 4224;
    float* s_si = shbuf + 6336;
    float* s_or = shbuf + 8448;
    float* s_op = shbuf + 10560;
    #pragma unroll
    for (int p = 0; p < 4; ++p){
      int t = tid + p*512, g = b*T_ + t, ix = idx32(t);
      s_la[ix] = log_anchor[g];
      s_um[ix] = unit_mask[g];
      s_sm[ix] = sealed_mask[g];
      s_si[ix] = silence_mask[g];
    }
    __syncthreads();
    if (tid < 64){
      const float CE = (float)(1.0 - 0.95);
      const int base = tid*32;
      float A = 1.f, Bv = 0.f, S = 0.f;
      for (int j = 0; j < 32; ++j){
        int ix = idx32(base + j);
        float mask   = clamp01(s_um[ix]);
        float sealed = clamp01(s_sm[ix]);
        float sil    = clamp01(s_si[ix])*mask;
        float speech = mask*sealed*(1.f-sil);
        float cm = CE*speech;
        A  = (1.f-cm)*A;
        Bv = (1.f-cm)*Bv + cm*s_la[ix];
        S += speech;
      }
      float Ai=A, Bi=Bv, Si=S;
      for (int off = 1; off < 64; off <<= 1){
        float Ap=__shfl_up(Ai,off), Bp=__shfl_up(Bi,off), Sp=__shfl_up(Si,off);
        if (tid >= off){ Bi = Ai*Bp + Bi; Ai *= Ap; Si += Sp; }
      }
      float Ae=__shfl_up(Ai,1), Be=__shfl_up(Bi,1), Se=__shfl_up(Si,1);
      if (tid==0){ Ae=1.f; Be=0.f; Se=0.f; }
      float r  = Ae*local_rate_ema[b] + Be;
      float ps = Se;
      for (int j = 0; j < 32; ++j){
        int ix = idx32(base + j);
        float mask   = clamp01(s_um[ix]);
        float sealed = clamp01(s_sm[ix]);
        float sil    = clamp01(s_si[ix])*mask;
        float speech = mask*sealed*(1.f-sil);
        s_or[ix] = r;
        s_op[ix] = ps;
        r  += CE*speech*(s_la[ix]-r);
        ps += speech;
      }
    }
    __syncthreads();
    #pragma unroll
    for (int p = 0; p < 4; ++p){
      int t = tid + p*512, g = b*T_ + t, ix = idx32(t);
      lr_seq[g]      = s_or[ix];
      prefix_prev[g] = s_op[ix];
    }

  } else {
    const int kt = blk - 144;
    unsigned short* sb = (unsigned short*)shbuf;   // [32][512]
    #pragma unroll
    for (int p = 0; p < 32; ++p){
      int id = tid + p*512;
      int kl = id >> 9, col = id & 511;
      sb[kl*512 + col] = bf16_rne(rW1[(kt*32 + kl)*512 + col]);
    }
    __syncthreads();
    const int col = tid;
    unsigned q[16];
    #pragma unroll
    for (int p = 0; p < 16; ++p)
      q[p] = (unsigned)sb[(2*p)*512 + col] | ((unsigned)sb[(2*p+1)*512 + col] << 16);
    uint4* dst = (uint4*)(BtG + kt*BSLAB + col*BCS);   // 80B rows (last 16B pad unused)
    dst[0] = make_uint4(q[0], q[1], q[2], q[3]);
    dst[1] = make_uint4(q[4], q[5], q[6], q[7]);
    dst[2] = make_uint4(q[8], q[9], q[10], q[11]);
    dst[3] = make_uint4(q[12], q[13], q[14], q[15]);
  }
}

// ---------------------------------------------------------------------------
// P2: 256 blocks x 512 threads.
//  blk   0..127 : spk_pb[b, slice] = sc@rW1[512:1024,slice] + rb1
//  blk 128..255 : cpart[b][s] = sum_slice gelu(ac)*cW2   (coarse partials)
// ---------------------------------------------------------------------------
__global__ __launch_bounds__(512) void k_p2(
    const float* __restrict__ spk_ctx, const float* __restrict__ global_rate,
    const float* __restrict__ cW1, const float* __restrict__ cb1,
    const float* __restrict__ cW2, const float* __restrict__ rW1,
    const float* __restrict__ rb1,
    float* __restrict__ spk_pb, float* __restrict__ cpart)
{
  __shared__ float sc[512];
  __shared__ float partial[32*64];
  const int tid = threadIdx.x;
  const int blk = blockIdx.x;
  const bool isAC = blk >= 128;
  const int bb = isAC ? (blk - 128) : blk;
  const int b = bb >> 3, s = bb & 7, n0 = s*64;

  sc[tid] = spk_ctx[b*512 + tid];
  __syncthreads();
  const int nq = tid & 15, q = tid >> 4;
  const float* mat = isAC ? cW1 : (rW1 + 512*512);
  float a0=0.f, a1=0.f, a2=0.f, a3=0.f;
  const float* wp = mat + (q*16)*512 + n0 + nq*4;
  #pragma unroll
  for (int kk = 0; kk < 16; ++kk){
    float sv = sc[q*16 + kk];
    float4 v = *(const float4*)(wp + kk*512);
    a0 = fmaf(sv, v.x, a0); a1 = fmaf(sv, v.y, a1);
    a2 = fmaf(sv, v.z, a2); a3 = fmaf(sv, v.w, a3);
  }
  *(float4*)&partial[q*64 + nq*4] = make_float4(a0,a1,a2,a3);
  __syncthreads();
  if (tid < 64){
    const int n = n0 + tid;
    float acc = 0.f;
    #pragma unroll
    for (int qq = 0; qq < 32; ++qq) acc += partial[qq*64 + tid];
    if (!isAC){
      spk_pb[b*512 + n] = acc + rb1[n];
    } else {
      float ac = acc + cb1[n] + global_rate[b]*cW1[512*512 + n];
      float g  = gelu_exact(ac)*cW2[n];
      g += __shfl_xor(g,1);  g += __shfl_xor(g,2);  g += __shfl_xor(g,4);
      g += __shfl_xor(g,8);  g += __shfl_xor(g,16); g += __shfl_xor(g,32);
      if (tid == 0) cpart[b*8 + s] = g;
    }
  }
}

// ---------------------------------------------------------------------------
// K3: MFMA heavy kernel, T3-minimal 2-phase pipeline.
// 256 blocks x 512 thr (8 waves) = 1 resident generation. Tile 128 rows x 512 cols.
// Wave (wh=w>>2, wc=w&3): 64 rows x 128 cols -> acc[4][8] (128 AGPR).
// B: pre-transposed padded slabs, global_load_lds double-buffer;
//    stage(kt+1) issued BEFORE MFMA(kt); ONE barrier per kt (never drains a
//    fresh stage). A: computed in 2 half-K phases into 264-stride LDS.
// LDS ~154 KB -> 1 block/CU. __launch_bounds__(512,2): 256-reg cap, no spill.
// ---------------------------------------------------------------------------
__global__ __launch_bounds__(512, 2) void k_heavy(
    const int*   __restrict__ content_units, const float* __restrict__ log_anchor,
    const float* __restrict__ unit_mask,     const float* __restrict__ sealed_mask,
    const float* __restrict__ sep_hint,      const float* __restrict__ edge_cue,
    const float* __restrict__ global_rate,   const float* __restrict__ silence_mask,
    const float* __restrict__ embed,         const float* __restrict__ feat_W,
    const float* __restrict__ feat_b,        const float* __restrict__ rW1,
    const float* __restrict__ rW2,           const float* __restrict__ rb2,
    const float* __restrict__ cb2,
    const float* __restrict__ lr_seq,        const float* __restrict__ prefix_prev,
    const float* __restrict__ spk_pb,        const float* __restrict__ cpart,
    const unsigned short* __restrict__ BtG,
    float* __restrict__ out)
{
  __shared__ __align__(16) unsigned short As_s[128*ASP];   // 67584 B
  __shared__ __align__(16) unsigned short Bs_s[2*BSLAB];   // 81920 B
  __shared__ float r_la[128], r_lr[128], r_sil[128], r_sep[128], r_edge[128], r_mask[128];
  __shared__ int   r_u[128];
  __shared__ float r_gt[128], r_speech[128], r_silc[128], r_resmul[128], r_tau[128];
  __shared__ float pdred[4][128];

  const int m0   = blockIdx.x*128;
  const int b    = m0 >> 11;
  const int tid  = threadIdx.x;
  const int lane = tid & 63;
  const int w    = tid >> 6;                // 0..7
  const int wh   = w >> 2, wc = w & 3;
  const int l15  = lane & 15, kg = lane >> 4;

  if (tid < 128){
    int m = m0 + tid;
    float csum = cb2[0];
    #pragma unroll
    for (int s = 0; s < 8; ++s) csum += cpart[b*8 + s];
    float coarse = 0.2f*tanhf(csum);
    float mask   = clamp01(unit_mask[m]);
    float sealed = clamp01(sealed_mask[m]);
    float sil    = clamp01(silence_mask[m])*mask;
    float commit = mask*sealed;
    float silc   = commit*sil;
    float speech = commit*(1.f-sil);
    float la = log_anchor[m];
    float lr = lr_seq[m];
    float gap = clampf(global_rate[b]-lr, -0.35f, 0.35f)*commit;
    float gt  = (gap + coarse*commit)*commit;
    float cold = clamp01(prefix_prev[m]*0.5f);
    float dur  = expf(la);
    float shortv = clamp01(fmaxf(dur,1.f)-1.f);
    r_la[tid]=la; r_lr[tid]=lr; r_sil[tid]=sil;
    r_sep[tid]=sep_hint[m]; r_edge[tid]=edge_cue[m]; r_mask[tid]=mask;
    r_u[tid]=content_units[m];
    r_gt[tid]=gt; r_speech[tid]=speech; r_silc[tid]=silc;
    r_resmul[tid]=cold*shortv*speech;
    r_tau[tid]=0.35f*((dur<2.0f)?0.35f:1.0f);
  }
  __syncthreads();

  f32x4 acc[4][8];
  #pragma unroll
  for (int r=0;r<4;++r)
    #pragma unroll
    for (int c=0;c<8;++c) acc[r][c] = (f32x4)0.0f;

  // ---- stage kt=0 into buf0 (overlaps A-compute half 0) ----
  {
    const unsigned short* src = BtG + w*2560 + lane*8;
    #pragma unroll
    for (int i = 0; i < 5; ++i)
      __builtin_amdgcn_global_load_lds(
        (const __attribute__((address_space(1))) unsigned int*)(src + i*512),
        (__attribute__((address_space(3))) unsigned int*)(&Bs_s[w*2560 + i*512]),
        16, 0, 0);
  }

  const int rowg = tid >> 4, ksl = tid & 15;    // A-compute: 4 rows x 16 k

  // ================= half 0 =================
  #pragma unroll
  for (int c8 = 0; c8 < 2; ++c8){
    const int jg = ksl*16 + c8*8;
    float4 w0a = *(const float4*)(feat_W + jg),        w0b = *(const float4*)(feat_W + jg + 4);
    float4 w1a = *(const float4*)(feat_W + 512 + jg),  w1b = *(const float4*)(feat_W + 512 + jg + 4);
    float4 w2a = *(const float4*)(feat_W + 1024 + jg), w2b = *(const float4*)(feat_W + 1024 + jg + 4);
    float4 w3a = *(const float4*)(feat_W + 1536 + jg), w3b = *(const float4*)(feat_W + 1536 + jg + 4);
    float4 w4a = *(const float4*)(feat_W + 2048 + jg), w4b = *(const float4*)(feat_W + 2048 + jg + 4);
    float4 ba  = *(const float4*)(feat_b + jg),        bb4 = *(const float4*)(feat_b + jg + 4);
    #pragma unroll
    for (int i = 0; i < 4; ++i){
      const int row = rowg*4 + i;
      const int u = r_u[row];
      const float la=r_la[row], lr=r_lr[row], si=r_sil[row],
                  sp=r_sep[row], ed=r_edge[row], mk=r_mask[row];
      const float* eb = embed + (size_t)u*DIM_ + jg;
      float4 ea = *(const float4*)eb, eb4v = *(const float4*)(eb + 4);
      float f0 = ea.x + ba.x + la*w0a.x + lr*w1a.x + si*w2a.x + sp*w3a.x + ed*w4a.x;
      float f1 = ea.y + ba.y + la*w0a.y + lr*w1a.y + si*w2a.y + sp*w3a.y + ed*w4a.y;
      float f2 = ea.z + ba.z + la*w0a.z + lr*w1a.z + si*w2a.z + sp*w3a.z + ed*w4a.z;
      float f3 = ea.w + ba.w + la*w0a.w + lr*w1a.w + si*w2a.w + sp*w3a.w + ed*w4a.w;
      float f4 = eb4v.x + bb4.x + la*w0b.x + lr*w1b.x + si*w2b.x + sp*w3b.x + ed*w4b.x;
      float f5 = eb4v.y + bb4.y + la*w0b.y + lr*w1b.y + si*w2b.y + sp*w3b.y + ed*w4b.y;
      float f6 = eb4v.z + bb4.z + la*w0b.z + lr*w1b.z + si*w2b.z + sp*w3b.z + ed*w4b.z;
      float f7 = eb4v.w + bb4.w + la*w0b.w + lr*w1b.w + si*w2b.w + sp*w3b.w + ed*w4b.w;
      unsigned p0 = cvt_pk_bf16(fast_tanh(f0)*mk, fast_tanh(f1)*mk);
      unsigned p1 = cvt_pk_bf16(fast_tanh(f2)*mk, fast_tanh(f3)*mk);
      unsigned p2 = cvt_pk_bf16(fast_tanh(f4)*mk, fast_tanh(f5)*mk);
      unsigned p3 = cvt_pk_bf16(fast_tanh(f6)*mk, fast_tanh(f7)*mk);
      *(uint4*)&As_s[row*ASP + ksl*16 + c8*8] = make_uint4(p0,p1,p2,p3);
    }
  }
  __syncthreads();   // drains stage(0) + A writes

  #pragma unroll 2
  for (int kt = 0; kt < 8; ++kt){
    {  // stage kt+1 -> buf (kt+1)&1  (kt=7 stages kt=8, B independent of A-half)
      const int ktn = kt + 1;
      const unsigned short* src = BtG + ktn*BSLAB + w*2560 + lane*8;
      #pragma unroll
      for (int i = 0; i < 5; ++i)
        __builtin_amdgcn_global_load_lds(
          (const __attribute__((address_space(1))) unsigned int*)(src + i*512),
          (__attribute__((address_space(3))) unsigned int*)(&Bs_s[(ktn&1)*BSLAB + w*2560 + i*512]),
          16, 0, 0);
    }
    short8_t af[4], bfr[8];
    #pragma unroll
    for (int r=0;r<4;++r)
      af[r] = *(const short8_t*)&As_s[(wh*64 + r*16 + l15)*ASP + kt*32 + kg*8];
    #pragma unroll
    for (int c=0;c<8;++c)
      bfr[c] = *(const short8_t*)&Bs_s[(kt&1)*BSLAB + (wc*128 + c*16 + l15)*BCS + kg*8];
    #pragma unroll
    for (int r=0;r<4;++r)
      #pragma unroll
      for (int c=0;c<8;++c)
        acc[r][c] = __builtin_amdgcn_mfma_f32_16x16x32_bf16(af[r], bfr[c], acc[r][c], 0, 0, 0);
    __syncthreads();
  }

  // ================= half 1 =================
  #pragma unroll
  for (int c8 = 0; c8 < 2; ++c8){
    const int jg = 256 + ksl*16 + c8*8;
    float4 w0a = *(const float4*)(feat_W + jg),        w0b = *(const float4*)(feat_W + jg + 4);
    float4 w1a = *(const float4*)(feat_W + 512 + jg),  w1b = *(const float4*)(feat_W + 512 + jg + 4);
    float4 w2a = *(const float4*)(feat_W + 1024 + jg), w2b = *(const float4*)(feat_W + 1024 + jg + 4);
    float4 w3a = *(const float4*)(feat_W + 1536 + jg), w3b = *(const float4*)(feat_W + 1536 + jg + 4);
    float4 w4a = *(const float4*)(feat_W + 2048 + jg), w4b = *(const float4*)(feat_W + 2048 + jg + 4);
    float4 ba  = *(const float4*)(feat_b + jg),        bb4 = *(const float4*)(feat_b + jg + 4);
    #pragma unroll
    for (int i = 0; i < 4; ++i){
      const int row = rowg*4 + i;
      const int u = r_u[row];
      const float la=r_la[row], lr=r_lr[row], si=r_sil[row],
                  sp=r_sep[row], ed=r_edge[row], mk=r_mask[row];
      const float* eb = embed + (size_t)u*DIM_ + jg;
      float4 ea = *(const float4*)eb, eb4v = *(const float4*)(eb + 4);
      float f0 = ea.x + ba.x + la*w0a.x + lr*w1a.x + si*w2a.x + sp*w3a.x + ed*w4a.x;
      float f1 = ea.y + ba.y + la*w0a.y + lr*w1a.y + si*w2a.y + sp*w3a.y + ed*w4a.y;
      float f2 = ea.z + ba.z + la*w0a.z + lr*w1a.z + si*w2a.z + sp*w3a.z + ed*w4a.z;
      float f3 = ea.w + ba.w + la*w0a.w + lr*w1a.w + si*w2a.w + sp*w3a.w + ed*w4a.w;
      float f4 = eb4v.x + bb4.x + la*w0b.x + lr*w1b.x + si*w2b.x + sp*w3b.x + ed*w4b.x;
      float f5 = eb4v.y + bb4.y + la*w0b.y + lr*w1b.y + si*w2b.y + sp*w3b.y + ed*w4b.y;
      float f6 = eb4v.z + bb4.z + la*w0b.z + lr*w1b.z + si*w2b.z + sp*w3b.z + ed*w4b.z;
      float f7 = eb4v.w + bb4.w + la*w0b.w + lr*w1b.w + si*w2b.w + sp*w3b.w + ed*w4b.w;
      unsigned p0 = cvt_pk_bf16(fast_tanh(f0)*mk, fast_tanh(f1)*mk);
      unsigned p1 = cvt_pk_bf16(fast_tanh(f2)*mk, fast_tanh(f3)*mk);
      unsigned p2 = cvt_pk_bf16(fast_tanh(f4)*mk, fast_tanh(f5)*mk);
      unsigned p3 = cvt_pk_bf16(fast_tanh(f6)*mk, fast_tanh(f7)*mk);
      *(uint4*)&As_s[row*ASP + ksl*16 + c8*8] = make_uint4(p0,p1,p2,p3);
    }
  }
  __syncthreads();   // drains stage(8) + A writes

  #pragma unroll 2
  for (int kt = 8; kt < 16; ++kt){
    if (kt < 15){
      const int ktn = kt + 1;
      const unsigned short* src = BtG + ktn*BSLAB + w*2560 + lane*8;
      #pragma unroll
      for (int i = 0; i < 5; ++i)
        __builtin_amdgcn_global_load_lds(
          (const __attribute__((address_space(1))) unsigned int*)(src + i*512),
          (__attribute__((address_space(3))) unsigned int*)(&Bs_s[(ktn&1)*BSLAB + w*2560 + i*512]),
          16, 0, 0);
    }
    short8_t af[4], bfr[8];
    #pragma unroll
    for (int r=0;r<4;++r)
      af[r] = *(const short8_t*)&As_s[(wh*64 + r*16 + l15)*ASP + (kt-8)*32 + kg*8];
    #pragma unroll
    for (int c=0;c<8;++c)
      bfr[c] = *(const short8_t*)&Bs_s[(kt&1)*BSLAB + (wc*128 + c*16 + l15)*BCS + kg*8];
    #pragma unroll
    for (int r=0;r<4;++r)
      #pragma unroll
      for (int c=0;c<8;++c)
        acc[r][c] = __builtin_amdgcn_mfma_f32_16x16x32_bf16(af[r], bfr[c], acc[r][c], 0, 0, 0);
    __syncthreads();
  }

  // --- epilogue: x = acc + spk_pb[col] + gt[row]*wb[col]; gelu; dot rW2 ---
  const int colb = wc*128 + l15;
  float stv[8], wbv[8], w2v[8];
  #pragma unroll
  for (int c=0;c<8;++c){
    int col = colb + c*16;
    stv[c] = spk_pb[b*DIM_ + col];
    wbv[c] = rW1[1024*DIM_ + col];
    w2v[c] = rW2[col];
  }
  #pragma unroll
  for (int r=0;r<4;++r){
    #pragma unroll
    for (int g=0; g<4; ++g){
      int lrow = wh*64 + r*16 + kg*4 + g;  // C/D: row=(lane>>4)*4+reg
      float gt = r_gt[lrow];
      float s = 0.f;
      #pragma unroll
      for (int c=0;c<8;++c){
        float x = acc[r][c][g] + stv[c] + gt*wbv[c];
        s += gelu_fast(x)*w2v[c];
      }
      s += __shfl_xor(s,1); s += __shfl_xor(s,2);
      s += __shfl_xor(s,4); s += __shfl_xor(s,8);
      if (l15 == 0) pdred[wc][lrow] = s;
    }
  }
  __syncthreads();
  if (tid < 128){
    float v = rb2[0] + pdred[0][tid] + pdred[1][tid] + pdred[2][tid] + pdred[3][tid];
    float residual = 0.35f*tanhf(v) * r_resmul[tid];
    float gt = r_gt[tid];
    out[m0+tid] = clampf(gt + residual, -1.2f, 1.2f)*r_speech[tid]
                + clampf(gt, -r_tau[tid], r_tau[tid])*r_silc[tid];
  }
}

// ---------------------------------------------------------------------------
extern "C" void kernel_launch(void* const* d_in, const int* in_sizes, int n_in,
                              void* d_out, int out_size, void* d_ws, size_t ws_size,
                              hipStream_t stream)
{
  const int*   content_units  = (const int*)  d_in[0];
  const float* log_anchor     = (const float*)d_in[1];
  const float* unit_mask      = (const float*)d_in[2];
  const float* sealed_mask    = (const float*)d_in[3];
  const float* sep_hint       = (const float*)d_in[4];
  const float* edge_cue       = (const float*)d_in[5];
  const float* global_rate    = (const float*)d_in[6];
  const float* local_rate_ema = (const float*)d_in[7];
  const float* silence_mask   = (const float*)d_in[8];
  const float* spk_embed      = (const float*)d_in[9];
  const float* embed          = (const float*)d_in[10];
  const float* feat_W         = (const float*)d_in[11];
  const float* feat_b         = (const float*)d_in[12];
  const float* spk_W          = (const float*)d_in[13];
  const float* spk_b          = (const float*)d_in[14];
  const float* cW1            = (const float*)d_in[15];
  const float* cb1            = (const float*)d_in[16];
  const float* cW2            = (const float*)d_in[17];
  const float* cb2            = (const float*)d_in[18];
  const float* rW1            = (const float*)d_in[19];
  const float* rb1            = (const float*)d_in[20];
  const float* rW2            = (const float*)d_in[21];
  const float* rb2            = (const float*)d_in[22];
  float* out = (float*)d_out;

  // ws (floats): lr_seq 32768 | prefix 32768 | spk_ctx 8192 | spk_pb 8192 |
  // cpart 128 | BtG bf16 16*20480 shorts = 655,360 B. Total ~983 KB.
  float* ws       = (float*)d_ws;
  float* lr_seq   = ws;
  float* prefix   = ws + 32768;
  float* spk_ctx  = ws + 65536;
  float* spk_pb   = ws + 73728;
  float* cpart    = ws + 81920;
  unsigned short* BtG = (unsigned short*)(ws + 82048);

  k_p1<<<160, 512, 0, stream>>>(log_anchor, unit_mask, sealed_mask, silence_mask,
                                local_rate_ema, spk_embed, spk_W, spk_b, rW1,
                                lr_seq, prefix, spk_ctx, BtG);
  k_p2<<<256, 512, 0, stream>>>(spk_ctx, global_rate, cW1, cb1, cW2, rW1, rb1,
                                spk_pb, cpart);
  k_heavy<<<M_/128, 512, 0, stream>>>(content_units, log_anchor, unit_mask, sealed_mask,
                                      sep_hint, edge_cue, global_rate, silence_mask,
                                      embed, feat_W, feat_b, rW1, rW2, rb2, cb2,
                                      lr_seq, prefix, spk_pb, cpart, BtG, out);
}